// Round 1
// baseline (416.040 us; speedup 1.0000x reference)
//
#include <hip/hip_runtime.h>

#define B_ 256
#define T_ 512
#define N_ 128

// Forward algorithm in scaled-exp domain.
// One block per batch b. 256 threads: j = tid&127 (output state), h = tid>>7
// (which half of the i-contraction this thread covers).
// Thread (j,h) holds e[k] = exp(trans[h*64+k][j]) in 64 VGPRs.
// q (scaled exp of alpha) lives in LDS, double-buffered; broadcast-read via
// float4 (ds_read_b128, same address across the wave -> conflict-free).
// Rescale by the max only every 4th step (fp32 range analysis: growth per
// step <= ~3e4, 4 steps <= ~1e21 << 3.4e38).
__global__ __launch_bounds__(256) void crf_forward_kernel(
    const float* __restrict__ lp,      // [B,T,N]
    const float* __restrict__ trans,   // [N,N]
    const float* __restrict__ startt,  // [N]
    const float* __restrict__ endt,    // [N]
    const int*   __restrict__ lengths, // [B]
    float*       __restrict__ out)     // [B]
{
    const int b   = blockIdx.x;
    const int tid = threadIdx.x;
    const int j   = tid & (N_ - 1);
    const int h   = tid >> 7;          // 0 or 1
    const int wid = tid >> 6;          // wave id 0..3

    __shared__ __align__(16) float q[2][N_];
    __shared__ float part[256];
    __shared__ float red[4];

    // Preload exp(transition) half-column into registers (one-time, coalesced
    // per row: consecutive j -> consecutive addresses).
    float e[64];
    #pragma unroll
    for (int k = 0; k < 64; ++k)
        e[k] = expf(trans[(h * 64 + k) * N_ + j]);

    const float* lpb = lp + (size_t)b * T_ * N_;
    const int len = lengths[b];        // in [T/2, T], so len >= 2 always

    float eend = 0.f;
    if (h == 0) eend = expf(endt[j]);

    // t = 0 init: q = exp(start + emit0), M = 0
    if (h == 0) q[0][j] = expf(startt[j] + lpb[j]);
    __syncthreads();

    float Macc = 0.f;
    int cur = 0;

    // software-prefetch of the emission row for step t
    float emit = (h == 0) ? lpb[N_ + j] : 0.f;   // t = 1

    for (int t = 1; t < len; ++t) {
        // prefetch next emission row (hides HBM/L2 latency behind the matvec)
        float emit_nxt = 0.f;
        if (h == 0 && (t + 1) < len) emit_nxt = lpb[(size_t)(t + 1) * N_ + j];

        // half-column matvec: partial_j^h = sum_{k} q[h*64+k] * e[k]
        const float4* q4 = (const float4*)(&q[cur][h * 64]);
        float a0 = 0.f, a1 = 0.f, a2 = 0.f, a3 = 0.f;
        #pragma unroll
        for (int k = 0; k < 16; ++k) {
            float4 qv = q4[k];
            a0 = fmaf(qv.x, e[4 * k + 0], a0);
            a1 = fmaf(qv.y, e[4 * k + 1], a1);
            a2 = fmaf(qv.z, e[4 * k + 2], a2);
            a3 = fmaf(qv.w, e[4 * k + 3], a3);
        }
        part[tid] = (a0 + a1) + (a2 + a3);
        __syncthreads();                        // B1: partials visible

        const int nxt = cur ^ 1;
        const bool resc = ((t & 3) == 0);       // block-uniform branch
        float v = 0.f;
        if (h == 0) {
            float s = part[j] + part[j + 128];
            v = s * expf(emit);
            if (resc) {
                float wm = v;
                #pragma unroll
                for (int off = 32; off > 0; off >>= 1)
                    wm = fmaxf(wm, __shfl_xor(wm, off));
                if ((tid & 63) == 0) red[wid] = wm;
            } else {
                q[nxt][j] = v;
            }
        }
        __syncthreads();                        // B2: q[nxt] (or red) visible
        if (resc) {
            if (h == 0) {
                float m = fmaxf(red[0], red[1]);
                q[nxt][j] = v * __builtin_amdgcn_rcpf(m);
                Macc += logf(m);
            }
            __syncthreads();                    // B3: rescaled q visible
        }
        cur = nxt;
        emit = emit_nxt;
    }

    // log_z = Macc + log( sum_j q_j * exp(end_j) )
    float fv = 0.f;
    if (h == 0) {
        fv = q[cur][j] * eend;
        #pragma unroll
        for (int off = 32; off > 0; off >>= 1)
            fv += __shfl_xor(fv, off);
        if ((tid & 63) == 0) red[wid] = fv;
    }
    __syncthreads();
    if (tid == 0) {
        out[b] = -(Macc + logf(red[0] + red[1]));
    }
}

// Path score: sum of gathered emissions + transitions + start + end.
// One wave per batch; runs after the forward kernel (same stream) and
// accumulates into out[b] which already holds -log_z.
__global__ __launch_bounds__(64) void crf_score_kernel(
    const float* __restrict__ lp,
    const float* __restrict__ trans,
    const float* __restrict__ startt,
    const float* __restrict__ endt,
    const int*   __restrict__ target,  // [B,T]
    const int*   __restrict__ lengths, // [B]
    float*       __restrict__ out)     // [B]
{
    const int b    = blockIdx.x;
    const int lane = threadIdx.x;
    const int len  = lengths[b];
    const int* tg  = target + b * T_;
    const float* lpb = lp + (size_t)b * T_ * N_;

    float acc = 0.f;
    for (int t = lane; t < len; t += 64) {
        int c = tg[t];
        acc += lpb[t * N_ + c];
        if (t + 1 < len) acc += trans[c * N_ + tg[t + 1]];
    }
    #pragma unroll
    for (int off = 32; off > 0; off >>= 1)
        acc += __shfl_xor(acc, off);
    if (lane == 0) {
        out[b] += acc + startt[tg[0]] + endt[tg[len - 1]];
    }
}

extern "C" void kernel_launch(void* const* d_in, const int* in_sizes, int n_in,
                              void* d_out, int out_size, void* d_ws, size_t ws_size,
                              hipStream_t stream) {
    const float* lp     = (const float*)d_in[0];
    const float* trans  = (const float*)d_in[1];
    const float* st     = (const float*)d_in[2];
    const float* en     = (const float*)d_in[3];
    const int*   target = (const int*)d_in[4];
    const int*   lens   = (const int*)d_in[5];
    float* out = (float*)d_out;

    crf_forward_kernel<<<B_, 256, 0, stream>>>(lp, trans, st, en, lens, out);
    crf_score_kernel<<<B_, 64, 0, stream>>>(lp, trans, st, en, target, lens, out);
}

// Round 2
// 357.783 us; speedup vs baseline: 1.1628x; 1.1628x over previous
//
#include <hip/hip_runtime.h>

#define B_ 256
#define T_ 512
#define N_ 128

// s_barrier WITHOUT the vmcnt(0) drain that __syncthreads() emits.
// LDS producer/consumer ordering only needs lgkmcnt(0); global prefetches
// (emissions) stay in flight across the barrier. "memory" clobber keeps the
// compiler from caching/reordering LDS accesses across it.
__device__ __forceinline__ void barrier_lds() {
    asm volatile("s_waitcnt lgkmcnt(0)\n\ts_barrier" ::: "memory");
}

// One block (256 threads, 4 waves) per batch.
// Lane pair (2m, 2m+1) of wave w owns output state j = 32w + m; the pair
// splits the 128-term contraction in half (64 FMA each) and combines with a
// single __shfl_xor — no LDS round-trip, ONE barrier per timestep.
// q is kept in scaled-exp domain; every 4th step it is rescaled by the
// previous step's q[0] (broadcast LDS read, no reduction), folded linearly
// into the matvec. Macc accumulates the log of the applied scales
// (uniform across the block).
__global__ __launch_bounds__(256, 1) void crf_fused_kernel(
    const float* __restrict__ lp,      // [B,T,N]
    const float* __restrict__ trans,   // [N,N]
    const float* __restrict__ startt,  // [N]
    const float* __restrict__ endt,    // [N]
    const int*   __restrict__ target,  // [B,T]
    const int*   __restrict__ lengths, // [B]
    float*       __restrict__ out)     // [B]
{
    const int b   = blockIdx.x;
    const int tid = threadIdx.x;
    const int w   = tid >> 6;          // wave 0..3
    const int l   = tid & 63;
    const int j   = (w << 5) | (l >> 1);   // output state 0..127
    const int h   = l & 1;                 // contraction half

    __shared__ __align__(16) float q[2][N_];
    __shared__ float red[8];

    // e[k] = exp(trans[64h + k][j]) — one-time preload into 64 VGPRs
    float e[64];
    {
        const float* tc = trans + (h << 6) * N_ + j;
        #pragma unroll
        for (int k = 0; k < 64; ++k)
            e[k] = __expf(tc[k * N_]);
    }

    const float* lpb = lp + (size_t)b * (T_ * N_);
    const int len = lengths[b];            // in [256, 512]

    const float eend = __expf(endt[j]);

    if (h == 0) q[0][j] = __expf(startt[j] + lpb[j]);
    barrier_lds();

    float Macc = 0.f;
    int cur = 0;
    // emission prefetch pipeline, distance 2 (stays in flight across raw barriers)
    float em0 = lpb[N_ + j];               // for t=1
    float em1 = lpb[2 * N_ + j];           // for t=2 (len >= 256, always valid)

    for (int t = 1; t < len; ++t) {
        float em2 = 0.f;
        if (t + 2 < len) em2 = lpb[(size_t)(t + 2) * N_ + j];

        // half-contraction matvec: s^h_j = sum_k q[64h+k] * e[k]
        // (pair of lanes reads two addresses per b128 -> 2-way aliasing, free)
        const float4* q4 = (const float4*)(&q[cur][h << 6]);
        float a0 = 0.f, a1 = 0.f, a2 = 0.f, a3 = 0.f;
        #pragma unroll
        for (int k = 0; k < 16; ++k) {
            float4 qv = q4[k];
            a0 = fmaf(qv.x, e[4 * k + 0], a0);
            a1 = fmaf(qv.y, e[4 * k + 1], a1);
            a2 = fmaf(qv.z, e[4 * k + 2], a2);
            a3 = fmaf(qv.w, e[4 * k + 3], a3);
        }
        float s = (a0 + a1) + (a2 + a3);
        s += __shfl_xor(s, 1);             // combine the pair's halves

        if ((t & 3) == 0) {                // deferred rescale, block-uniform
            float sc = q[cur][0];          // broadcast LDS read
            s *= __builtin_amdgcn_rcpf(sc);
            Macc += __logf(sc);
        }

        float v = s * __expf(em0);
        if (h == 0) q[cur ^ 1][j] = v;
        barrier_lds();

        cur ^= 1;
        em0 = em1; em1 = em2;
    }

    // ---- log Z: Macc + log(sum_j q_j * exp(end_j)) ----
    float f = (h == 0) ? q[cur][j] * eend : 0.f;   // odd lanes are duplicates
    #pragma unroll
    for (int off = 32; off > 0; off >>= 1) f += __shfl_xor(f, off);

    // ---- path score (gathers), all 256 threads ----
    const int* tg = target + b * T_;
    float acc = 0.f;
    for (int t = tid; t < len; t += 256) {
        int c = tg[t];
        acc += lpb[t * N_ + c];
        if (t + 1 < len) acc += trans[c * N_ + tg[t + 1]];
    }
    #pragma unroll
    for (int off = 32; off > 0; off >>= 1) acc += __shfl_xor(acc, off);

    if (l == 0) { red[w] = f; red[4 + w] = acc; }
    __syncthreads();
    if (tid == 0) {
        float z   = red[0] + red[1] + red[2] + red[3];
        float sc  = red[4] + red[5] + red[6] + red[7];
        float logz = Macc + __logf(z);
        out[b] = sc + startt[tg[0]] + endt[tg[len - 1]] - logz;
    }
}

extern "C" void kernel_launch(void* const* d_in, const int* in_sizes, int n_in,
                              void* d_out, int out_size, void* d_ws, size_t ws_size,
                              hipStream_t stream) {
    const float* lp     = (const float*)d_in[0];
    const float* trans  = (const float*)d_in[1];
    const float* st     = (const float*)d_in[2];
    const float* en     = (const float*)d_in[3];
    const int*   target = (const int*)d_in[4];
    const int*   lens   = (const int*)d_in[5];
    float* out = (float*)d_out;

    crf_fused_kernel<<<B_, 256, 0, stream>>>(lp, trans, st, en, target, lens, out);
}

// Round 3
// 273.848 us; speedup vs baseline: 1.5192x; 1.3065x over previous
//
#include <hip/hip_runtime.h>

#define B_ 256
#define T_ 512
#define N_ 128

// Barrier that drains only LDS (lgkmcnt), NOT vmcnt: global prefetches stay
// in flight across it (plain __syncthreads() emits vmcnt(0) and kills the
// emission prefetch pipeline).
__device__ __forceinline__ void barrier_lds() {
    asm volatile("s_waitcnt lgkmcnt(0)\n\ts_barrier" ::: "memory");
}

__device__ __forceinline__ float readlane_f(float v, int k) {
    return __int_as_float(__builtin_amdgcn_readlane(__float_as_int(v), k));
}

// One block per batch. 4 waves; wave w owns contraction quarter
// i in [32w, 32w+32). Each lane covers outputs j = l and j = 64+l.
// q broadcast = v_readlane -> SGPR -> v_fma scalar operand (no LDS).
// Only LDS use: combining the 4 quarter partials (double-buffered, one
// barrier/step). Next-step q redistribution: one in-register __shfl.
__global__ __launch_bounds__(256, 1) void crf_fused_kernel(
    const float* __restrict__ lp,      // [B,T,N]
    const float* __restrict__ trans,   // [N,N]
    const float* __restrict__ startt,  // [N]
    const float* __restrict__ endt,    // [N]
    const int*   __restrict__ target,  // [B,T]
    const int*   __restrict__ lengths, // [B]
    float*       __restrict__ out)     // [B]
{
    const int b   = blockIdx.x;
    const int tid = threadIdx.x;
    const int w   = tid >> 6;          // wave 0..3 = i-quarter
    const int l   = tid & 63;

    __shared__ float part[2][4][N_];   // [parity][wave][j]
    __shared__ float red[8];

    // e0[k] = exp(trans[32w+k][l]), e1[k] = exp(trans[32w+k][64+l])
    float e0[32], e1[32];
    {
        const float* tq = trans + (w << 5) * N_;
        #pragma unroll
        for (int k = 0; k < 32; ++k) {
            e0[k] = __expf(tq[k * N_ + l]);
            e1[k] = __expf(tq[k * N_ + 64 + l]);
        }
    }

    const float* lpb = lp + (size_t)b * (T_ * N_);
    const int len = lengths[b];        // in [256, 512]

    // t = 0 alphas in exp domain (replicated in every wave)
    float v0 = __expf(startt[l]      + lpb[l]);
    float v1 = __expf(startt[64 + l] + lpb[64 + l]);

    // wave w needs q[32w + (l&31)] each step: source lane/register is static
    const int sidx = ((w & 1) << 5) | (l & 31);
    float v_q = __shfl((w >= 2) ? v1 : v0, sidx);

    float Macc = 0.f;

    // emission prefetch pipeline, distance 2 (len >= 256 so rows 1,2 valid)
    float cur0 = lpb[N_ + l],     cur1 = lpb[N_ + 64 + l];
    float nx0  = lpb[2 * N_ + l], nx1  = lpb[2 * N_ + 64 + l];

    for (int t = 1; t < len; ++t) {
        const int tp = min(t + 2, T_ - 1);        // clamp: always in-bounds
        float nn0 = lpb[(size_t)tp * N_ + l];
        float nn1 = lpb[(size_t)tp * N_ + 64 + l];

        // hoist emission exps off the post-combine critical chain
        float eexp0 = __expf(cur0);
        float eexp1 = __expf(cur1);

        // quarter contraction via SGPR broadcast: 32 readlane + 64 fma
        float a0 = 0.f, a1 = 0.f, c0 = 0.f, c1 = 0.f;
        #pragma unroll
        for (int k = 0; k < 32; k += 2) {
            float s0 = readlane_f(v_q, k);
            float s1 = readlane_f(v_q, k + 1);
            a0 = fmaf(s0, e0[k],     a0);
            a1 = fmaf(s0, e1[k],     a1);
            c0 = fmaf(s1, e0[k + 1], c0);
            c1 = fmaf(s1, e1[k + 1], c1);
        }
        float p0 = a0 + c0;
        float p1 = a1 + c1;

        const int pb = t & 1;
        part[pb][w][l]      = p0;
        part[pb][w][64 + l] = p1;
        barrier_lds();                 // ONE barrier per step

        float s0t = p0, s1t = p1;
        #pragma unroll
        for (int d = 1; d < 4; ++d) {
            const int ow = (w + d) & 3;
            s0t += part[pb][ow][l];
            s1t += part[pb][ow][64 + l];
        }

        if ((t & 3) == 0) {            // deferred rescale (block-uniform)
            float sc  = readlane_f(s0t, 0);       // combined s_{j=0}
            float isc = __builtin_amdgcn_rcpf(sc);
            s0t *= isc;
            s1t *= isc;
            Macc += __logf(sc);
        }

        v0 = s0t * eexp0;
        v1 = s1t * eexp1;
        v_q = __shfl((w >= 2) ? v1 : v0, sidx);   // next step's q quarter

        cur0 = nx0; cur1 = nx1; nx0 = nn0; nx1 = nn1;
    }

    // ---- log Z from wave 0's replica ----
    if (w == 0) {
        float f = v0 * __expf(endt[l]) + v1 * __expf(endt[64 + l]);
        #pragma unroll
        for (int off = 32; off > 0; off >>= 1) f += __shfl_xor(f, off);
        if (l == 0) red[0] = Macc + __logf(f);
    }

    // ---- path score (gathers), all 256 threads ----
    const int* tg = target + b * T_;
    float acc = 0.f;
    for (int t = tid; t < len; t += 256) {
        int c = tg[t];
        acc += lpb[t * N_ + c];
        if (t + 1 < len) acc += trans[c * N_ + tg[t + 1]];
    }
    #pragma unroll
    for (int off = 32; off > 0; off >>= 1) acc += __shfl_xor(acc, off);
    if (l == 0) red[4 + w] = acc;
    __syncthreads();

    if (tid == 0) {
        float sc = red[4] + red[5] + red[6] + red[7];
        out[b] = sc + startt[tg[0]] + endt[tg[len - 1]] - red[0];
    }
}

extern "C" void kernel_launch(void* const* d_in, const int* in_sizes, int n_in,
                              void* d_out, int out_size, void* d_ws, size_t ws_size,
                              hipStream_t stream) {
    const float* lp     = (const float*)d_in[0];
    const float* trans  = (const float*)d_in[1];
    const float* st     = (const float*)d_in[2];
    const float* en     = (const float*)d_in[3];
    const int*   target = (const int*)d_in[4];
    const int*   lens   = (const int*)d_in[5];
    float* out = (float*)d_out;

    crf_fused_kernel<<<B_, 256, 0, stream>>>(lp, trans, st, en, target, lens, out);
}